// Round 8
// baseline (3875.658 us; speedup 1.0000x reference)
//
#include <hip/hip_runtime.h>

#define T_ 64
#define B_ 64
#define S_ 128
#define E_ 512
#define H_ 1024
#define BH (B_ * H_)

// LDS weight slice geometry (bf16 elements), +8 pad => row stride = 4 banks
#define W0ROW (E_ + 2 * H_ + 8)   // 2568
#define W1ROW (2 * H_ + 8)        // 2056
#define SMEM_BYTES ((16 * W0ROW + 16 * W1ROW) * 2)  // 147968 B

typedef __attribute__((ext_vector_type(8))) short short8;
typedef __attribute__((ext_vector_type(4))) short short4v;
typedef __attribute__((ext_vector_type(4))) float f32x4;

static __device__ __forceinline__ float bf2f(ushort u) {
  union { float f; unsigned u; } x; x.u = ((unsigned)u) << 16; return x.f;
}
static __device__ __forceinline__ ushort f2bf(float f) {
  union { float f; unsigned u; } x; x.f = f;
  unsigned r = 0x7FFFu + ((x.u >> 16) & 1u);
  return (ushort)((x.u + r) >> 16);
}
static __device__ __forceinline__ float sigm(float x) {
  return 1.f / (1.f + expf(-x));
}

// device-scope (sc1) relaxed atomics: write-through to the coherence point.
static __device__ __forceinline__ void st32_dev(unsigned* p, unsigned v) {
  __hip_atomic_store(p, v, __ATOMIC_RELAXED, __HIP_MEMORY_SCOPE_AGENT);
}
static __device__ __forceinline__ unsigned ld32_dev(const unsigned* p) {
  return __hip_atomic_load(p, __ATOMIC_RELAXED, __HIP_MEMORY_SCOPE_AGENT);
}
static __device__ __forceinline__ void stf_dev(float* p, float v) {
  union { float f; unsigned u; } x; x.f = v;
  st32_dev((unsigned*)p, x.u);
}
static __device__ __forceinline__ void add_dev(unsigned* p) {
  __hip_atomic_fetch_add(p, 1u, __ATOMIC_RELAXED, __HIP_MEMORY_SCOPE_AGENT);
}

// ---------------------------------------------------------------------------
__global__ __launch_bounds__(256) void k_cvt(const float* __restrict__ src,
                                             ushort* __restrict__ dst, int n4) {
  int i = blockIdx.x * 256 + threadIdx.x;
  if (i >= n4) return;
  f32x4 v = ((const f32x4*)src)[i];
  short4v o;
  o[0] = (short)f2bf(v[0]); o[1] = (short)f2bf(v[1]);
  o[2] = (short)f2bf(v[2]); o[3] = (short)f2bf(v[3]);
  ((short4v*)dst)[i] = o;
}

// ---------------------------------------------------------------------------
__global__ __launch_bounds__(256) void k_zero(unsigned* __restrict__ p, int n) {
  int i = blockIdx.x * 256 + threadIdx.x;
  if (i < n) p[i] = 0;
}

// ---------------------------------------------------------------------------
// f32 (H,H) [k][d]  ->  bf16 (H,H) [d][k]  (transpose + convert, LDS tiled)
__global__ __launch_bounds__(256) void k_cvtT(const float* __restrict__ src,
                                              ushort* __restrict__ dst) {
  __shared__ ushort tile[32][33];
  const int bx = blockIdx.x & 31;   // d-tile
  const int by = blockIdx.x >> 5;   // k-tile
  const int lx = threadIdx.x & 31, ly = threadIdx.x >> 5;  // 32 x 8
#pragma unroll
  for (int i = 0; i < 32; i += 8)
    tile[ly + i][lx] = f2bf(src[(size_t)(by * 32 + ly + i) * H_ + bx * 32 + lx]);
  __syncthreads();
#pragma unroll
  for (int i = 0; i < 32; i += 8)
    dst[(size_t)(bx * 32 + ly + i) * H_ + by * 32 + lx] = tile[lx][ly + i];
}

// ---------------------------------------------------------------------------
// ctxp[m, d] = sum_k ctx[m, k] * WaT[d, k],  m = s*B+b.  bf16 output.
__global__ __launch_bounds__(256) void k_ctxp(const ushort* __restrict__ ctx,
                                              const ushort* __restrict__ WaT,
                                              ushort* __restrict__ ctxp) {
  const int tid = threadIdx.x;
  const int wave = tid >> 6, lane = tid & 63;
  const int quad = lane >> 4, l16 = lane & 15;
  const int m0 = blockIdx.x * 64 + wave * 16;
  const int n0 = blockIdx.y * 64;
  const ushort* ar = ctx + (size_t)(m0 + l16) * H_;
  const int koff = quad * 8;
  f32x4 acc[4] = {};
  for (int k0 = 0; k0 < H_; k0 += 32) {
    int kk = k0 + koff;
    short8 a = *(const short8*)(ar + kk);
#pragma unroll
    for (int nt = 0; nt < 4; ++nt) {
      short8 b = *(const short8*)(WaT + (size_t)(n0 + nt * 16 + l16) * H_ + kk);
      acc[nt] = __builtin_amdgcn_mfma_f32_16x16x32_bf16(a, b, acc[nt], 0, 0, 0);
    }
  }
#pragma unroll
  for (int nt = 0; nt < 4; ++nt)
#pragma unroll
    for (int r = 0; r < 4; ++r)
      ctxp[(size_t)(m0 + quad * 4 + r) * H_ + n0 + nt * 16 + l16] =
          f2bf(acc[nt][r]);
}

// ---------------------------------------------------------------------------
// ctxo[m, j] = sum_d ctx[m, d] * Wout[j, d]  (first-H cols of Wout).  bf16.
__global__ __launch_bounds__(256) void k_ctxo(const ushort* __restrict__ ctx,
                                              const ushort* __restrict__ Wout,
                                              ushort* __restrict__ ctxo) {
  const int tid = threadIdx.x;
  const int wave = tid >> 6, lane = tid & 63;
  const int quad = lane >> 4, l16 = lane & 15;
  const int m0 = blockIdx.x * 64 + wave * 16;
  const int n0 = blockIdx.y * 64;
  const ushort* ar = ctx + (size_t)(m0 + l16) * H_;
  const int koff = quad * 8;
  f32x4 acc[4] = {};
  for (int k0 = 0; k0 < H_; k0 += 32) {
    int kk = k0 + koff;
    short8 a = *(const short8*)(ar + kk);
#pragma unroll
    for (int nt = 0; nt < 4; ++nt) {
      short8 b = *(const short8*)(Wout +
                                  (size_t)(n0 + nt * 16 + l16) * (2 * H_) + kk);
      acc[nt] = __builtin_amdgcn_mfma_f32_16x16x32_bf16(a, b, acc[nt], 0, 0, 0);
    }
  }
#pragma unroll
  for (int nt = 0; nt < 4; ++nt)
#pragma unroll
    for (int r = 0; r < 4; ++r)
      ctxo[(size_t)(m0 + quad * 4 + r) * H_ + n0 + nt * 16 + l16] =
          f2bf(acc[nt][r]);
}

// ---------------------------------------------------------------------------
__global__ __launch_bounds__(256) void k_init(const float* __restrict__ h0in,
                                              ushort* __restrict__ h0b,
                                              ushort* __restrict__ h1b,
                                              ushort* __restrict__ fdb,
                                              unsigned* __restrict__ flags) {
  int i = blockIdx.x * 256 + threadIdx.x;
  h0b[i] = f2bf(h0in[i]);
  h1b[i] = f2bf(h0in[BH + i]);
  fdb[i] = 0;
  if (blockIdx.x == 0) flags[threadIdx.x * 16] = 0;
}

// ---------------------------------------------------------------------------
// Grid barrier (round-3 proven): block 0 collects per-block arrival flags,
// broadcasts via flags[0]. sc1 stores reach the coherence point;
// __syncthreads drains vmcnt. No cache-invalidating fences.
static __device__ __forceinline__ void grid_bar(unsigned* flags, unsigned gen) {
  __syncthreads();
  if (blockIdx.x == 0) {
    const int tid = threadIdx.x;
    if (tid > 0 && tid < 256) {
      while (ld32_dev(&flags[tid * 16]) < gen) __builtin_amdgcn_s_sleep(4);
    }
    __syncthreads();
    if (tid == 0) st32_dev(&flags[0], gen);
    __syncthreads();
  } else {
    if (threadIdx.x == 0) {
      st32_dev(&flags[blockIdx.x * 16], gen);
      while (ld32_dev(&flags[0]) < gen) __builtin_amdgcn_s_sleep(4);
    }
    __syncthreads();
  }
  asm volatile("" ::: "memory");
}

// ---------------------------------------------------------------------------
struct FusedP {
  const ushort* inp;
  const ushort* Wih0; const ushort* Whh0;
  const ushort* Wih1; const ushort* Whh1;
  const ushort* Wout;
  const ushort* ctxp;    // bf16 (S,B,H)  = ctx @ Wa
  const ushort* ctxo;    // bf16 (S,B,H)  = ctx @ Wout_c^T
  const float* bih0; const float* bhh0;
  const float* bih1; const float* bhh1;
  const float* c0in;
  ushort* h0b;   // (T_+1) rotated (B,H) bf16 buffers -- write-once
  ushort* h1b;   // (T_+1)
  ushort* fdb;   // (T_+1)
  float* psb;    // (T_) rotated (B,S,4) f32 partial scores -- write-once
  float* gemmb;  // (T_) rotated (B,H) f32 h1@Wout_h^T -- write-once
  unsigned* done;   // (T_,64) x16 pad: score-partial arrival counters
  unsigned* gdone;  // (T_,4)  x16 pad: gemm arrival counters
  float* outs; float* hF; float* cF; float* attns;
  unsigned* flags;
};

// st/red union over ub[]:  st[w][r][c] (8x16x17)  /  red[sg][i] (4x256)
#define ST(w, r, c) ub[(w) * 272 + (r) * 17 + (c)]
#define RED(w, i)   ub[(w) * 256 + (i)]

// Persistent kernel: 256 blocks x 1024 threads (4 waves/SIMD).
// 3 global barriers/step: P1 | P2 | {P3 scores+gemm -> local counters -> P4
// softmax+attn-sum+combine} | barrier. P4's producer wait is a 1-hop poll of
// done[t][b3] (4 score writers) + gdone[t][dq] (16 gemm writers).
__global__ __launch_bounds__(1024, 1) void k_fused(FusedP p) {
  extern __shared__ ushort wlds[];          // [16*W0ROW] + [16*W1ROW]
  ushort* w0 = wlds;
  ushort* w1 = wlds + 16 * W0ROW;
  __shared__ float ub[2176];                // st / red union (8704 B)
  __shared__ float al[S_];
  const int blk = blockIdx.x;
  const int tid = threadIdx.x;
  const int wave = tid >> 6, lane = tid & 63;
  const int wg = wave & 3;                  // batch strip
  const int kh = wave >> 2;                 // K-quarter
  const int quad = lane >> 4, l16 = lane & 15;
  const int j0 = blk * 4;

  // ---- stage this block's weight slice into LDS (once) ----
  for (int idx = tid; idx < 16 * 192; idx += 1024) {   // Wih0
    int r = idx / 192, c = (idx % 192) * 8;
    int n = (r >> 2) * H_ + j0 + (r & 3);
    *(short8*)(w0 + r * W0ROW + c) =
        *(const short8*)(p.Wih0 + (size_t)n * (E_ + H_) + c);
  }
  for (int idx = tid; idx < 16 * 128; idx += 1024) {   // Whh0
    int r = idx / 128, c = (idx % 128) * 8;
    int n = (r >> 2) * H_ + j0 + (r & 3);
    *(short8*)(w0 + r * W0ROW + (E_ + H_) + c) =
        *(const short8*)(p.Whh0 + (size_t)n * H_ + c);
  }
  for (int idx = tid; idx < 16 * 128; idx += 1024) {   // Wih1
    int r = idx / 128, c = (idx % 128) * 8;
    int n = (r >> 2) * H_ + j0 + (r & 3);
    *(short8*)(w1 + r * W1ROW + c) =
        *(const short8*)(p.Wih1 + (size_t)n * H_ + c);
  }
  for (int idx = tid; idx < 16 * 128; idx += 1024) {   // Whh1
    int r = idx / 128, c = (idx % 128) * 8;
    int n = (r >> 2) * H_ + j0 + (r & 3);
    *(short8*)(w1 + r * W1ROW + H_ + c) =
        *(const short8*)(p.Whh1 + (size_t)n * H_ + c);
  }
  __syncthreads();

  // cell ownership (tid<256): cell = tid -> b = tid>>2, jl = tid&3
  const int own_b = tid >> 2;
  const int own_jl = tid & 3;
  const int own_j = j0 + own_jl;
  const int own_idx = own_b * H_ + own_j;
  float c0reg = 0.f, c1reg = 0.f;
  float b0i = 0.f, b0f = 0.f, b0g = 0.f, b0o = 0.f;
  float b1i = 0.f, b1f = 0.f, b1g = 0.f, b1o = 0.f;
  if (tid < 256) {
    c0reg = p.c0in[own_idx];
    c1reg = p.c0in[BH + own_idx];
    b0i = p.bih0[own_j]          + p.bhh0[own_j];
    b0f = p.bih0[H_ + own_j]     + p.bhh0[H_ + own_j];
    b0g = p.bih0[2 * H_ + own_j] + p.bhh0[2 * H_ + own_j];
    b0o = p.bih0[3 * H_ + own_j] + p.bhh0[3 * H_ + own_j];
    b1i = p.bih1[own_j]          + p.bhh1[own_j];
    b1f = p.bih1[H_ + own_j]     + p.bhh1[H_ + own_j];
    b1g = p.bih1[2 * H_ + own_j] + p.bhh1[2 * H_ + own_j];
    b1o = p.bih1[3 * H_ + own_j] + p.bhh1[3 * H_ + own_j];
  }

  const ushort* w0r = w0 + l16 * W0ROW;   // B-fragment row for MFMA
  const ushort* w1r = w1 + l16 * W1ROW;
  const int koff = quad * 8;

  // attention decomposition: this block owns (b3, d-quarter dq)
  const int b3 = blk >> 2, dq = blk & 3;
  const int d0 = dq * 256;

  unsigned gen = 0;

  for (int t = 0; t < T_; ++t) {
    const ushort* h0prev = p.h0b + (size_t)t * BH;
    ushort* h0new       = p.h0b + (size_t)(t + 1) * BH;
    const ushort* h1prev = p.h1b + (size_t)t * BH;
    ushort* h1new       = p.h1b + (size_t)(t + 1) * BH;
    const ushort* feedr  = p.fdb + (size_t)t * BH;
    ushort* feedw       = p.fdb + (size_t)(t + 1) * BH;
    float* pst          = p.psb + (size_t)t * B_ * S_ * 4;
    float* gemm_t       = p.gemmb + (size_t)t * BH;
    const int last = (t == T_ - 1);

    // ---- phase 1: LSTM layer 0, 4-way K-split ----
    {
      const int arow = 16 * wg + l16;
      const ushort* er = p.inp + ((size_t)t * B_ + arow) * E_;
      const ushort* fr = feedr + (size_t)arow * H_;
      const ushort* hr = h0prev + (size_t)arow * H_;
      const int kbase = kh * 640;           // (E+2H)/4
      f32x4 acc = {};
#pragma unroll
      for (int k0 = 0; k0 < 640; k0 += 32) {
        int kk = kbase + k0 + koff;
        short8 a;
        if (kk < E_)            a = *(const short8*)(er + kk);
        else if (kk < E_ + H_)  a = *(const short8*)(fr + (kk - E_));
        else                    a = *(const short8*)(hr + (kk - E_ - H_));
        short8 b = *(const short8*)(w0r + kk);
        acc = __builtin_amdgcn_mfma_f32_16x16x32_bf16(a, b, acc, 0, 0, 0);
      }
      if (kh >= 2) {
#pragma unroll
        for (int r = 0; r < 4; ++r) ST(wave - 8, quad * 4 + r, l16) = acc[r];
      }
      __syncthreads();
      if (kh < 2) {
#pragma unroll
        for (int r = 0; r < 4; ++r) {
          float s = ST(wave, quad * 4 + r, l16) + acc[r];
          ST(wave, quad * 4 + r, l16) = s;
        }
      }
      __syncthreads();
      if (tid < 256) {
        const int w = own_b >> 4, bl = own_b & 15;
        float gi = ST(w, bl, 0 + own_jl)  + ST(w + 4, bl, 0 + own_jl)  + b0i;
        float gf = ST(w, bl, 4 + own_jl)  + ST(w + 4, bl, 4 + own_jl)  + b0f;
        float gg = ST(w, bl, 8 + own_jl)  + ST(w + 4, bl, 8 + own_jl)  + b0g;
        float go = ST(w, bl, 12 + own_jl) + ST(w + 4, bl, 12 + own_jl) + b0o;
        float cn = sigm(gf) * c0reg + sigm(gi) * tanhf(gg);
        float hn = sigm(go) * tanhf(cn);
        c0reg = cn;
        if (last) { p.hF[own_idx] = hn; p.cF[own_idx] = cn; }
        unsigned u = f2bf(hn);
        unsigned up = __shfl_down(u, 1);
        if (!(own_jl & 1))
          st32_dev((unsigned*)h0new + own_b * (H_ / 2) + blk * 2 + (own_jl >> 1),
                   u | (up << 16));
      }
    }
    grid_bar(p.flags, ++gen);

    // ---- phase 2: LSTM layer 1, 4-way K-split ----
    {
      const int arow = 16 * wg + l16;
      const ushort* xr = h0new + (size_t)arow * H_;
      const ushort* hr = h1prev + (size_t)arow * H_;
      const int kbase = kh * 512;           // 2H/4
      f32x4 acc = {};
#pragma unroll
      for (int k0 = 0; k0 < 512; k0 += 32) {
        int kk = kbase + k0 + koff;
        short8 a = (kk < H_) ? *(const short8*)(xr + kk)
                             : *(const short8*)(hr + (kk - H_));
        short8 b = *(const short8*)(w1r + kk);
        acc = __builtin_amdgcn_mfma_f32_16x16x32_bf16(a, b, acc, 0, 0, 0);
      }
      if (kh >= 2) {
#pragma unroll
        for (int r = 0; r < 4; ++r) ST(wave - 8, quad * 4 + r, l16) = acc[r];
      }
      __syncthreads();
      if (kh < 2) {
#pragma unroll
        for (int r = 0; r < 4; ++r) {
          float s = ST(wave, quad * 4 + r, l16) + acc[r];
          ST(wave, quad * 4 + r, l16) = s;
        }
      }
      __syncthreads();
      if (tid < 256) {
        const int w = own_b >> 4, bl = own_b & 15;
        float gi = ST(w, bl, 0 + own_jl)  + ST(w + 4, bl, 0 + own_jl)  + b1i;
        float gf = ST(w, bl, 4 + own_jl)  + ST(w + 4, bl, 4 + own_jl)  + b1f;
        float gg = ST(w, bl, 8 + own_jl)  + ST(w + 4, bl, 8 + own_jl)  + b1g;
        float go = ST(w, bl, 12 + own_jl) + ST(w + 4, bl, 12 + own_jl) + b1o;
        float cn = sigm(gf) * c1reg + sigm(gi) * tanhf(gg);
        float hn = sigm(go) * tanhf(cn);
        c1reg = cn;
        if (last) { p.hF[BH + own_idx] = hn; p.cF[BH + own_idx] = cn; }
        unsigned u = f2bf(hn);
        unsigned up = __shfl_down(u, 1);
        if (!(own_jl & 1))
          st32_dev((unsigned*)h1new + own_b * (H_ / 2) + blk * 2 + (own_jl >> 1),
                   u | (up << 16));
      }
    }
    grid_bar(p.flags, ++gen);

    // ---- phase 3: partial scores (all) + h1@Wout_h^T (blocks 0..63) ----
    {
      // scores: 16 waves x 8 s over this block's d-quarter
      short4v qv = *(const short4v*)(h1new + (size_t)b3 * H_ + d0 + lane * 4);
      float q0 = bf2f((ushort)qv[0]), q1 = bf2f((ushort)qv[1]);
      float q2 = bf2f((ushort)qv[2]), q3 = bf2f((ushort)qv[3]);
#pragma unroll
      for (int i = 0; i < 8; ++i) {
        const int s = wave * 8 + i;
        short4v v = *(const short4v*)(p.ctxp + ((size_t)s * B_ + b3) * H_ +
                                      d0 + lane * 4);
        float pr = bf2f((ushort)v[0]) * q0 + bf2f((ushort)v[1]) * q1 +
                   bf2f((ushort)v[2]) * q2 + bf2f((ushort)v[3]) * q3;
#pragma unroll
        for (int off = 32; off; off >>= 1) pr += __shfl_down(pr, off);
        if (lane == 0) stf_dev(pst + (b3 * S_ + s) * 4 + dq, pr);
      }
      // gemm: blocks 0..63 own 16 j-cols, K=1024 (h1 half of Wout)
      if (blk < 64) {
        const int pj0 = blk * 16;
        const int arow = 16 * wg + l16;
        const ushort* hr2 = h1new + (size_t)arow * H_;
        const ushort* wr = p.Wout + (size_t)(pj0 + l16) * (2 * H_) + H_;
        const int kbase = kh * 256;
        f32x4 acc = {};
#pragma unroll
        for (int k0 = 0; k0 < 256; k0 += 32) {
          int kk = kbase + k0 + koff;
          acc = __builtin_amdgcn_mfma_f32_16x16x32_bf16(
              *(const short8*)(hr2 + kk), *(const short8*)(wr + kk), acc,
              0, 0, 0);
        }
        if (kh >= 2) {
#pragma unroll
          for (int r = 0; r < 4; ++r) ST(wave - 8, quad * 4 + r, l16) = acc[r];
        }
        __syncthreads();
        if (kh < 2) {
#pragma unroll
          for (int r = 0; r < 4; ++r) {
            float s = ST(wave, quad * 4 + r, l16) + acc[r];
            ST(wave, quad * 4 + r, l16) = s;
          }
        }
        __syncthreads();
        {
          const int b = tid >> 4;
          const int jl = tid & 15;
          const int w = b >> 4, bl = b & 15;
          stf_dev(gemm_t + b * H_ + pj0 + jl,
                  ST(w, bl, jl) + ST(w + 4, bl, jl));
        }
      }
      __syncthreads();   // drain all sc1 stores (vmcnt(0) before s_barrier)
      if (tid == 0) {
        add_dev(p.done + (((unsigned)(t << 6) + b3) << 4));
        if (blk < 64) add_dev(p.gdone + (((unsigned)(t << 2) + (blk >> 4)) << 4));
      }
    }

    // ---- phase 4: wait producers -> softmax + attn-sum + combine ----
    {
      if (tid == 0) {
        const unsigned* dp = p.done + (((unsigned)(t << 6) + b3) << 4);
        while (ld32_dev(dp) < 4) __builtin_amdgcn_s_sleep(2);
        const unsigned* gp = p.gdone + (((unsigned)(t << 2) + dq) << 4);
        while (ld32_dev(gp) < 16) __builtin_amdgcn_s_sleep(2);
      }
      __syncthreads();
      if (tid < S_) {
        f32x4 ps = *(const f32x4*)(pst + (b3 * S_ + tid) * 4);
        al[tid] = ps[0] + ps[1] + ps[2] + ps[3];
      }
      __syncthreads();
      if (wave == 0) {
        float m = fmaxf(al[lane], al[lane + 64]);
#pragma unroll
        for (int off = 32; off; off >>= 1) m = fmaxf(m, __shfl_down(m, off));
        m = __shfl(m, 0);
        float e0 = expf(al[lane] - m), e1 = expf(al[lane + 64] - m);
        float s2 = e0 + e1;
#pragma unroll
        for (int off = 32; off; off >>= 1) s2 += __shfl_down(s2, off);
        s2 = __shfl(s2, 0);
        float inv = 1.f / s2;
        al[lane] = e0 * inv;
        al[lane + 64] = e1 * inv;
      }
      __syncthreads();
      if (dq == 0 && tid < S_)
        p.attns[((size_t)t * B_ + b3) * S_ + tid] = al[tid];
      // attn-sum: thread (sg, jj): partial over s in [32sg, 32sg+32)
      {
        const int sg = tid >> 8, jj = tid & 255;
        const ushort* cop = p.ctxo + (size_t)b3 * H_ + d0 + jj;
        float a0 = 0.f;
#pragma unroll
        for (int i = 0; i < 32; ++i) {
          int s = sg * 32 + i;
          a0 += al[s] * bf2f(cop[(size_t)s * B_ * H_]);
        }
        RED(sg, jj) = a0;
      }
      __syncthreads();
      if (tid < 256) {
        const int jj = tid;
        float val = RED(0, jj) + RED(1, jj) + RED(2, jj) + RED(3, jj) +
                    gemm_t[b3 * H_ + d0 + jj];
        float v = tanhf(val);
        p.outs[(size_t)t * B_ * H_ + b3 * H_ + d0 + jj] = v;
        unsigned u = f2bf(v);
        unsigned up = __shfl_down(u, 1);
        if (!(jj & 1))
          st32_dev((unsigned*)feedw + (b3 * H_ + d0 + jj) / 2, u | (up << 16));
      }
    }
    grid_bar(p.flags, ++gen);
  }
}

// ---------------------------------------------------------------------------
extern "C" void kernel_launch(void* const* d_in, const int* in_sizes, int n_in,
                              void* d_out, int out_size, void* d_ws, size_t ws_size,
                              hipStream_t stream) {
  const float* inpf  = (const float*)d_in[0];
  const float* ctxf  = (const float*)d_in[1];
  const float* h0in  = (const float*)d_in[2];
  const float* c0in  = (const float*)d_in[3];
  const float* Wih0f = (const float*)d_in[4];
  const float* bih0  = (const float*)d_in[5];
  const float* Whh0f = (const float*)d_in[6];
  const float* bhh0  = (const float*)d_in[7];
  const float* Wih1f = (const float*)d_in[8];
  const float* bih1  = (const float*)d_in[9];
  const float* Whh1f = (const float*)d_in[10];
  const float* bhh1  = (const float*)d_in[11];
  const float* Waf   = (const float*)d_in[12];
  const float* Woutf = (const float*)d_in[13];

  float* out = (float*)d_out;
  float* outs  = out;                              // (T,B,H)
  float* hF    = out + (size_t)T_ * B_ * H_;       // (2,B,H)
  float* cF    = hF + 2 * BH;                      // (2,B,H)
  float* attns = cF + 2 * BH;                      // (T,B,S)

  char* p = (char*)d_ws;
  auto take = [&](size_t bytes) -> char* {
    char* q = p;
    p += (bytes + 255) & ~(size_t)255;
    return q;
  };
  ushort* h0b  = (ushort*)take((size_t)(T_ + 1) * BH * 2);
  ushort* h1b  = (ushort*)take((size_t)(T_ + 1) * BH * 2);
  ushort* fdb  = (ushort*)take((size_t)(T_ + 1) * BH * 2);
  float* psb   = (float*)take((size_t)T_ * B_ * S_ * 4 * 4);
  float* gemmb = (float*)take((size_t)T_ * BH * 4);
  unsigned* done  = (unsigned*)take((size_t)T_ * 64 * 16 * 4);
  unsigned* gdone = (unsigned*)take((size_t)T_ * 4 * 16 * 4);
  unsigned* flags = (unsigned*)take(256 * 16 * sizeof(unsigned));
  ushort* WaT  = (ushort*)take((size_t)H_ * H_ * 2);
  ushort* ctxp = (ushort*)take((size_t)S_ * B_ * H_ * 2);
  ushort* ctxo = (ushort*)take((size_t)S_ * B_ * H_ * 2);

  struct { const float* src; int n; } cv[7] = {
    {Wih0f, 4 * H_ * (E_ + H_)}, {Whh0f, 4 * H_ * H_},
    {Wih1f, 4 * H_ * H_},        {Whh1f, 4 * H_ * H_},
    {Woutf, 2 * H_ * H_},
    {inpf,  T_ * B_ * E_},       {ctxf,  S_ * B_ * H_},
  };
  ushort* cb[7];
  for (int i = 0; i < 7; ++i) {
    cb[i] = (ushort*)take((size_t)cv[i].n * 2);
    int n4 = cv[i].n / 4;
    k_cvt<<<(n4 + 255) / 256, 256, 0, stream>>>(cv[i].src, cb[i], n4);
  }
  const ushort *Wih0 = cb[0], *Whh0 = cb[1], *Wih1 = cb[2], *Whh1 = cb[3],
               *Wout = cb[4], *inp = cb[5], *ctx = cb[6];

  k_cvtT<<<(H_ / 32) * (H_ / 32), 256, 0, stream>>>(Waf, WaT);
  k_ctxp<<<dim3((S_ * B_) / 64, H_ / 64), 256, 0, stream>>>(ctx, WaT, ctxp);
  k_ctxo<<<dim3((S_ * B_) / 64, H_ / 64), 256, 0, stream>>>(ctx, Wout, ctxo);
  {
    int nz = T_ * 64 * 16 + T_ * 4 * 16;   // done + gdone (contiguous)
    k_zero<<<(nz + 255) / 256, 256, 0, stream>>>(done, nz);
  }
  k_init<<<BH / 256, 256, 0, stream>>>(h0in, h0b, h1b, fdb, flags);

  static int smem_set = 0;
  if (!smem_set) {
    hipFuncSetAttribute((const void*)k_fused,
                        hipFuncAttributeMaxDynamicSharedMemorySize, SMEM_BYTES);
    smem_set = 1;
  }

  FusedP fp;
  fp.inp = inp; fp.Wih0 = Wih0; fp.Whh0 = Whh0; fp.Wih1 = Wih1; fp.Whh1 = Whh1;
  fp.Wout = Wout; fp.ctxp = ctxp; fp.ctxo = ctxo;
  fp.bih0 = bih0; fp.bhh0 = bhh0; fp.bih1 = bih1; fp.bhh1 = bhh1;
  fp.c0in = c0in;
  fp.h0b = h0b; fp.h1b = h1b; fp.fdb = fdb; fp.psb = psb; fp.gemmb = gemmb;
  fp.done = done; fp.gdone = gdone;
  fp.outs = outs; fp.hF = hF; fp.cF = cF; fp.attns = attns;
  fp.flags = flags;
  void* kargs[] = {(void*)&fp};
  hipLaunchCooperativeKernel(k_fused, dim3(256), dim3(1024), kargs,
                             (unsigned)SMEM_BYTES, stream);
}

// Round 11
// 3308.859 us; speedup vs baseline: 1.1713x; 1.1713x over previous
//
#include <hip/hip_runtime.h>

#define T_ 64
#define B_ 64
#define S_ 128
#define E_ 512
#define H_ 1024
#define BH (B_ * H_)

// LDS weight slice geometry (bf16 elements), +8 pad => row stride = 4 banks
#define W0ROW (E_ + 2 * H_ + 8)   // 2568
#define W1ROW (2 * H_ + 8)        // 2056
#define SMEM_BYTES ((16 * W0ROW + 16 * W1ROW) * 2)  // 147968 B

typedef __attribute__((ext_vector_type(8))) short short8;
typedef __attribute__((ext_vector_type(4))) short short4v;
typedef __attribute__((ext_vector_type(4))) float f32x4;

static __device__ __forceinline__ float bf2f(ushort u) {
  union { float f; unsigned u; } x; x.u = ((unsigned)u) << 16; return x.f;
}
static __device__ __forceinline__ ushort f2bf(float f) {
  union { float f; unsigned u; } x; x.f = f;
  unsigned r = 0x7FFFu + ((x.u >> 16) & 1u);
  return (ushort)((x.u + r) >> 16);
}
static __device__ __forceinline__ float sigm(float x) {
  return 1.f / (1.f + expf(-x));
}

// device-scope (sc1) relaxed atomics: write-through to the coherence point.
static __device__ __forceinline__ void st32_dev(unsigned* p, unsigned v) {
  __hip_atomic_store(p, v, __ATOMIC_RELAXED, __HIP_MEMORY_SCOPE_AGENT);
}
static __device__ __forceinline__ unsigned ld32_dev(const unsigned* p) {
  return __hip_atomic_load(p, __ATOMIC_RELAXED, __HIP_MEMORY_SCOPE_AGENT);
}
static __device__ __forceinline__ void stf_dev(float* p, float v) {
  union { float f; unsigned u; } x; x.f = v;
  st32_dev((unsigned*)p, x.u);
}

// ---------------------------------------------------------------------------
__global__ __launch_bounds__(256) void k_cvt(const float* __restrict__ src,
                                             ushort* __restrict__ dst, int n4) {
  int i = blockIdx.x * 256 + threadIdx.x;
  if (i >= n4) return;
  f32x4 v = ((const f32x4*)src)[i];
  short4v o;
  o[0] = (short)f2bf(v[0]); o[1] = (short)f2bf(v[1]);
  o[2] = (short)f2bf(v[2]); o[3] = (short)f2bf(v[3]);
  ((short4v*)dst)[i] = o;
}

// ---------------------------------------------------------------------------
// f32 (H,H) [k][d]  ->  bf16 (H,H) [d][k]  (transpose + convert, LDS tiled)
__global__ __launch_bounds__(256) void k_cvtT(const float* __restrict__ src,
                                              ushort* __restrict__ dst) {
  __shared__ ushort tile[32][33];
  const int bx = blockIdx.x & 31;   // d-tile
  const int by = blockIdx.x >> 5;   // k-tile
  const int lx = threadIdx.x & 31, ly = threadIdx.x >> 5;  // 32 x 8
#pragma unroll
  for (int i = 0; i < 32; i += 8)
    tile[ly + i][lx] = f2bf(src[(size_t)(by * 32 + ly + i) * H_ + bx * 32 + lx]);
  __syncthreads();
#pragma unroll
  for (int i = 0; i < 32; i += 8)
    dst[(size_t)(bx * 32 + ly + i) * H_ + by * 32 + lx] = tile[lx][ly + i];
}

// ---------------------------------------------------------------------------
// ctxp[m, d] = sum_k ctx[m, k] * WaT[d, k],  m = s*B+b.  bf16 output.
__global__ __launch_bounds__(256) void k_ctxp(const ushort* __restrict__ ctx,
                                              const ushort* __restrict__ WaT,
                                              ushort* __restrict__ ctxp) {
  const int tid = threadIdx.x;
  const int wave = tid >> 6, lane = tid & 63;
  const int quad = lane >> 4, l16 = lane & 15;
  const int m0 = blockIdx.x * 64 + wave * 16;
  const int n0 = blockIdx.y * 64;
  const ushort* ar = ctx + (size_t)(m0 + l16) * H_;
  const int koff = quad * 8;
  f32x4 acc[4] = {};
  for (int k0 = 0; k0 < H_; k0 += 32) {
    int kk = k0 + koff;
    short8 a = *(const short8*)(ar + kk);
#pragma unroll
    for (int nt = 0; nt < 4; ++nt) {
      short8 b = *(const short8*)(WaT + (size_t)(n0 + nt * 16 + l16) * H_ + kk);
      acc[nt] = __builtin_amdgcn_mfma_f32_16x16x32_bf16(a, b, acc[nt], 0, 0, 0);
    }
  }
#pragma unroll
  for (int nt = 0; nt < 4; ++nt)
#pragma unroll
    for (int r = 0; r < 4; ++r)
      ctxp[(size_t)(m0 + quad * 4 + r) * H_ + n0 + nt * 16 + l16] =
          f2bf(acc[nt][r]);
}

// ---------------------------------------------------------------------------
__global__ __launch_bounds__(256) void k_init(const float* __restrict__ h0in,
                                              ushort* __restrict__ h0b,
                                              ushort* __restrict__ h1b,
                                              ushort* __restrict__ fdb,
                                              unsigned* __restrict__ flags) {
  int i = blockIdx.x * 256 + threadIdx.x;
  h0b[i] = f2bf(h0in[i]);
  h1b[i] = f2bf(h0in[BH + i]);
  fdb[i] = 0;
  if (blockIdx.x == 0) flags[threadIdx.x * 16] = 0;
}

// ---------------------------------------------------------------------------
// Grid barrier (round-3/7 proven): block 0 collects per-block arrival flags,
// broadcasts via flags[0]. sc1 stores reach the coherence point;
// __syncthreads drains vmcnt. No cache-invalidating fences.
// 1024-thread blocks: only tid<256 poll in block 0 (256 blocks total).
static __device__ __forceinline__ void grid_bar(unsigned* flags, unsigned gen) {
  __syncthreads();
  if (blockIdx.x == 0) {
    const int tid = threadIdx.x;
    if (tid > 0 && tid < 256) {
      while (ld32_dev(&flags[tid * 16]) < gen) __builtin_amdgcn_s_sleep(4);
    }
    __syncthreads();
    if (tid == 0) st32_dev(&flags[0], gen);
    __syncthreads();
  } else {
    if (threadIdx.x == 0) {
      st32_dev(&flags[blockIdx.x * 16], gen);
      while (ld32_dev(&flags[0]) < gen) __builtin_amdgcn_s_sleep(4);
    }
    __syncthreads();
  }
  asm volatile("" ::: "memory");
}

// ---------------------------------------------------------------------------
struct FusedP {
  const ushort* inp;
  const ushort* Wih0; const ushort* Whh0;
  const ushort* Wih1; const ushort* Whh1;
  const ushort* Wout;
  const ushort* ctx;
  const ushort* ctxp;    // bf16 (S,B,H)
  const float* bih0; const float* bhh0;
  const float* bih1; const float* bhh1;
  const float* c0in;
  ushort* h0b;   // (T_+1) rotated (B,H) bf16 buffers -- write-once
  ushort* h1b;   // (T_+1)
  ushort* fdb;   // (T_+1)
  ushort* cvb;   // (T_)
  float* psb;    // (T_) rotated (B,S,4) f32 partial scores -- write-once
  float* outs; float* hF; float* cF; float* attns;
  unsigned* flags;
};

// st/red union over ub[]:  st[w][r][c] (8x16x17)  /  red[w][i] (8x256)
#define ST(w, r, c) ub[(w) * 272 + (r) * 17 + (c)]
#define RED(w, i)   ub[(w) * 256 + (i)]

// Persistent kernel: 256 blocks x 1024 threads (4 waves/SIMD), 5 barriers/
// step -- EXACT round-7 structure (hardware-proven). Single new change:
// ctxp/ctx per-thread slices are TIME-INVARIANT -> pinned in registers
// before the t-loop, so P3a/P3b do zero global reads in steady state.
__global__ __launch_bounds__(1024, 1) void k_fused(FusedP p) {
  extern __shared__ ushort wlds[];          // [16*W0ROW] + [16*W1ROW]
  ushort* w0 = wlds;
  ushort* w1 = wlds + 16 * W0ROW;
  __shared__ float ub[2176];                // st / red union (8704 B)
  __shared__ float al[S_];
  const int blk = blockIdx.x;
  const int tid = threadIdx.x;
  const int wave = tid >> 6, lane = tid & 63;
  const int wg = wave & 3;                  // batch strip
  const int kh = wave >> 2;                 // K-quarter
  const int quad = lane >> 4, l16 = lane & 15;
  const int j0 = blk * 4;

  // ---- stage this block's weight slice into LDS (once) ----
  for (int idx = tid; idx < 16 * 192; idx += 1024) {   // Wih0
    int r = idx / 192, c = (idx % 192) * 8;
    int n = (r >> 2) * H_ + j0 + (r & 3);
    *(short8*)(w0 + r * W0ROW + c) =
        *(const short8*)(p.Wih0 + (size_t)n * (E_ + H_) + c);
  }
  for (int idx = tid; idx < 16 * 128; idx += 1024) {   // Whh0
    int r = idx / 128, c = (idx % 128) * 8;
    int n = (r >> 2) * H_ + j0 + (r & 3);
    *(short8*)(w0 + r * W0ROW + (E_ + H_) + c) =
        *(const short8*)(p.Whh0 + (size_t)n * H_ + c);
  }
  for (int idx = tid; idx < 16 * 128; idx += 1024) {   // Wih1
    int r = idx / 128, c = (idx % 128) * 8;
    int n = (r >> 2) * H_ + j0 + (r & 3);
    *(short8*)(w1 + r * W1ROW + c) =
        *(const short8*)(p.Wih1 + (size_t)n * H_ + c);
  }
  for (int idx = tid; idx < 16 * 128; idx += 1024) {   // Whh1
    int r = idx / 128, c = (idx % 128) * 8;
    int n = (r >> 2) * H_ + j0 + (r & 3);
    *(short8*)(w1 + r * W1ROW + H_ + c) =
        *(const short8*)(p.Whh1 + (size_t)n * H_ + c);
  }
  __syncthreads();

  // cell ownership (tid<256): cell = tid -> b = tid>>2, jl = tid&3
  const int own_b = tid >> 2;
  const int own_jl = tid & 3;
  const int own_j = j0 + own_jl;
  const int own_idx = own_b * H_ + own_j;
  float c0reg = 0.f, c1reg = 0.f;
  float b0i = 0.f, b0f = 0.f, b0g = 0.f, b0o = 0.f;
  float b1i = 0.f, b1f = 0.f, b1g = 0.f, b1o = 0.f;
  if (tid < 256) {
    c0reg = p.c0in[own_idx];
    c1reg = p.c0in[BH + own_idx];
    b0i = p.bih0[own_j]          + p.bhh0[own_j];
    b0f = p.bih0[H_ + own_j]     + p.bhh0[H_ + own_j];
    b0g = p.bih0[2 * H_ + own_j] + p.bhh0[2 * H_ + own_j];
    b0o = p.bih0[3 * H_ + own_j] + p.bhh0[3 * H_ + own_j];
    b1i = p.bih1[own_j]          + p.bhh1[own_j];
    b1f = p.bih1[H_ + own_j]     + p.bhh1[H_ + own_j];
    b1g = p.bih1[2 * H_ + own_j] + p.bhh1[2 * H_ + own_j];
    b1o = p.bih1[3 * H_ + own_j] + p.bhh1[3 * H_ + own_j];
  }

  const ushort* w0r = w0 + l16 * W0ROW;   // B-fragment row for MFMA
  const ushort* w1r = w1 + l16 * W1ROW;
  const int koff = quad * 8;

  // attention decomposition: this block owns (b3, d-quarter dq)
  const int b3 = blk >> 2, dq = blk & 3;
  const int d0 = dq * 256;

  // ---- register-pinned attention slices (time-invariant) ----
  short4v cp[8], cx[8];
#pragma unroll
  for (int i = 0; i < 8; ++i) {
    const int s = wave * 8 + i;
    cp[i] = *(const short4v*)(p.ctxp + ((size_t)s * B_ + b3) * H_ +
                              d0 + lane * 4);
    cx[i] = *(const short4v*)(p.ctx + ((size_t)s * B_ + b3) * H_ +
                              d0 + lane * 4);
  }

  unsigned gen = 0;

  for (int t = 0; t < T_; ++t) {
    const ushort* h0prev = p.h0b + (size_t)t * BH;
    ushort* h0new       = p.h0b + (size_t)(t + 1) * BH;
    const ushort* h1prev = p.h1b + (size_t)t * BH;
    ushort* h1new       = p.h1b + (size_t)(t + 1) * BH;
    const ushort* feedr  = p.fdb + (size_t)t * BH;
    ushort* feedw       = p.fdb + (size_t)(t + 1) * BH;
    ushort* cv          = p.cvb + (size_t)t * BH;
    float* pst          = p.psb + (size_t)t * B_ * S_ * 4;
    const int last = (t == T_ - 1);

    // ---- phase 1: LSTM layer 0, 4-way K-split ----
    {
      const int arow = 16 * wg + l16;
      const ushort* er = p.inp + ((size_t)t * B_ + arow) * E_;
      const ushort* fr = feedr + (size_t)arow * H_;
      const ushort* hr = h0prev + (size_t)arow * H_;
      const int kbase = kh * 640;           // (E+2H)/4
      f32x4 acc = {};
#pragma unroll
      for (int k0 = 0; k0 < 640; k0 += 32) {
        int kk = kbase + k0 + koff;
        short8 a;
        if (kk < E_)            a = *(const short8*)(er + kk);
        else if (kk < E_ + H_)  a = *(const short8*)(fr + (kk - E_));
        else                    a = *(const short8*)(hr + (kk - E_ - H_));
        short8 b = *(const short8*)(w0r + kk);
        acc = __builtin_amdgcn_mfma_f32_16x16x32_bf16(a, b, acc, 0, 0, 0);
      }
      if (kh >= 2) {
#pragma unroll
        for (int r = 0; r < 4; ++r) ST(wave - 8, quad * 4 + r, l16) = acc[r];
      }
      __syncthreads();
      if (kh < 2) {
#pragma unroll
        for (int r = 0; r < 4; ++r) {
          float s = ST(wave, quad * 4 + r, l16) + acc[r];
          ST(wave, quad * 4 + r, l16) = s;
        }
      }
      __syncthreads();
      if (tid < 256) {
        const int w = own_b >> 4, bl = own_b & 15;
        float gi = ST(w, bl, 0 + own_jl)  + ST(w + 4, bl, 0 + own_jl)  + b0i;
        float gf = ST(w, bl, 4 + own_jl)  + ST(w + 4, bl, 4 + own_jl)  + b0f;
        float gg = ST(w, bl, 8 + own_jl)  + ST(w + 4, bl, 8 + own_jl)  + b0g;
        float go = ST(w, bl, 12 + own_jl) + ST(w + 4, bl, 12 + own_jl) + b0o;
        float cn = sigm(gf) * c0reg + sigm(gi) * tanhf(gg);
        float hn = sigm(go) * tanhf(cn);
        c0reg = cn;
        if (last) { p.hF[own_idx] = hn; p.cF[own_idx] = cn; }
        unsigned u = f2bf(hn);
        unsigned up = __shfl_down(u, 1);
        if (!(own_jl & 1))
          st32_dev((unsigned*)h0new + own_b * (H_ / 2) + blk * 2 + (own_jl >> 1),
                   u | (up << 16));
      }
    }
    grid_bar(p.flags, ++gen);

    // ---- phase 2: LSTM layer 1, 4-way K-split ----
    {
      const int arow = 16 * wg + l16;
      const ushort* xr = h0new + (size_t)arow * H_;
      const ushort* hr = h1prev + (size_t)arow * H_;
      const int kbase = kh * 512;           // 2H/4
      f32x4 acc = {};
#pragma unroll
      for (int k0 = 0; k0 < 512; k0 += 32) {
        int kk = kbase + k0 + koff;
        short8 a = (kk < H_) ? *(const short8*)(xr + kk)
                             : *(const short8*)(hr + (kk - H_));
        short8 b = *(const short8*)(w1r + kk);
        acc = __builtin_amdgcn_mfma_f32_16x16x32_bf16(a, b, acc, 0, 0, 0);
      }
      if (kh >= 2) {
#pragma unroll
        for (int r = 0; r < 4; ++r) ST(wave - 8, quad * 4 + r, l16) = acc[r];
      }
      __syncthreads();
      if (kh < 2) {
#pragma unroll
        for (int r = 0; r < 4; ++r) {
          float s = ST(wave, quad * 4 + r, l16) + acc[r];
          ST(wave, quad * 4 + r, l16) = s;
        }
      }
      __syncthreads();
      if (tid < 256) {
        const int w = own_b >> 4, bl = own_b & 15;
        float gi = ST(w, bl, 0 + own_jl)  + ST(w + 4, bl, 0 + own_jl)  + b1i;
        float gf = ST(w, bl, 4 + own_jl)  + ST(w + 4, bl, 4 + own_jl)  + b1f;
        float gg = ST(w, bl, 8 + own_jl)  + ST(w + 4, bl, 8 + own_jl)  + b1g;
        float go = ST(w, bl, 12 + own_jl) + ST(w + 4, bl, 12 + own_jl) + b1o;
        float cn = sigm(gf) * c1reg + sigm(gi) * tanhf(gg);
        float hn = sigm(go) * tanhf(cn);
        c1reg = cn;
        if (last) { p.hF[BH + own_idx] = hn; p.cF[BH + own_idx] = cn; }
        unsigned u = f2bf(hn);
        unsigned up = __shfl_down(u, 1);
        if (!(own_jl & 1))
          st32_dev((unsigned*)h1new + own_b * (H_ / 2) + blk * 2 + (own_jl >> 1),
                   u | (up << 16));
      }
    }
    grid_bar(p.flags, ++gen);

    // ---- phase 3a: partial scores from PINNED ctxp ----
    {
      short4v qv = *(const short4v*)(h1new + (size_t)b3 * H_ + d0 + lane * 4);
      float q0 = bf2f((ushort)qv[0]), q1 = bf2f((ushort)qv[1]);
      float q2 = bf2f((ushort)qv[2]), q3 = bf2f((ushort)qv[3]);
#pragma unroll
      for (int i = 0; i < 8; ++i) {
        const int s = wave * 8 + i;
        float pr = bf2f((ushort)cp[i][0]) * q0 + bf2f((ushort)cp[i][1]) * q1 +
                   bf2f((ushort)cp[i][2]) * q2 + bf2f((ushort)cp[i][3]) * q3;
#pragma unroll
        for (int off = 32; off; off >>= 1) pr += __shfl_down(pr, off);
        if (lane == 0) stf_dev(pst + (b3 * S_ + s) * 4 + dq, pr);
      }
    }
    grid_bar(p.flags, ++gen);

    // ---- phase 3b: reduce + softmax + cvec from PINNED ctx ----
    {
      if (tid < S_) {
        f32x4 ps = *(const f32x4*)(pst + (b3 * S_ + tid) * 4);
        al[tid] = ps[0] + ps[1] + ps[2] + ps[3];
      }
      __syncthreads();
      if (wave == 0) {
        float m = fmaxf(al[lane], al[lane + 64]);
#pragma unroll
        for (int off = 32; off; off >>= 1) m = fmaxf(m, __shfl_down(m, off));
        m = __shfl(m, 0);
        float e0 = expf(al[lane] - m), e1 = expf(al[lane + 64] - m);
        float s2 = e0 + e1;
#pragma unroll
        for (int off = 32; off; off >>= 1) s2 += __shfl_down(s2, off);
        s2 = __shfl(s2, 0);
        float inv = 1.f / s2;
        al[lane] = e0 * inv;
        al[lane + 64] = e1 * inv;
      }
      __syncthreads();
      if (dq == 0 && tid < S_)
        p.attns[((size_t)t * B_ + b3) * S_ + tid] = al[tid];
      // cvec over d-quarter: wave w covers s in [8w, 8w+8), 4 d per lane
      float a0 = 0.f, a1 = 0.f, a2 = 0.f, a3 = 0.f;
#pragma unroll
      for (int i = 0; i < 8; ++i) {
        const int s = wave * 8 + i;
        float w = al[s];
        a0 += w * bf2f((ushort)cx[i][0]);
        a1 += w * bf2f((ushort)cx[i][1]);
        a2 += w * bf2f((ushort)cx[i][2]);
        a3 += w * bf2f((ushort)cx[i][3]);
      }
      __syncthreads();   // al reads done; ub reuse safe
      if (wave >= 8) {
        RED(wave - 8, lane * 4 + 0) = a0;
        RED(wave - 8, lane * 4 + 1) = a1;
        RED(wave - 8, lane * 4 + 2) = a2;
        RED(wave - 8, lane * 4 + 3) = a3;
      }
      __syncthreads();
      if (wave < 8) {
        RED(wave, lane * 4 + 0) += a0;
        RED(wave, lane * 4 + 1) += a1;
        RED(wave, lane * 4 + 2) += a2;
        RED(wave, lane * 4 + 3) += a3;
      }
      __syncthreads();
      if (tid < 256) {
        float val = 0.f;
#pragma unroll
        for (int w = 0; w < 8; ++w) val += RED(w, tid);
        unsigned u = f2bf(val);
        unsigned up = __shfl_down(u, 1);
        if (!(tid & 1))
          st32_dev((unsigned*)cv + (b3 * H_ + d0 + tid) / 2, u | (up << 16));
      }
    }
    grid_bar(p.flags, ++gen);

    // ---- phase 4: output projection, blocks 0..63, 4-way K-split ----
    if (blk < 64) {
      const int pj0 = blk * 16;
      const int arow = 16 * wg + l16;
      const ushort* cr = cv + (size_t)arow * H_;
      const ushort* hr2 = h1new + (size_t)arow * H_;
      const ushort* wr = p.Wout + (size_t)(pj0 + l16) * (2 * H_);
      const int kbase = kh * 512;
      f32x4 acc = {};
#pragma unroll
      for (int k0 = 0; k0 < 512; k0 += 32) {
        int kk = kbase + k0 + koff;
        short8 a = (kk < H_) ? *(const short8*)(cr + kk)
                             : *(const short8*)(hr2 + (kk - H_));
        short8 b = *(const short8*)(wr + kk);
        acc = __builtin_amdgcn_mfma_f32_16x16x32_bf16(a, b, acc, 0, 0, 0);
      }
      if (kh >= 2) {
#pragma unroll
        for (int r = 0; r < 4; ++r) ST(wave - 8, quad * 4 + r, l16) = acc[r];
      }
      __syncthreads();
      if (kh < 2) {
#pragma unroll
        for (int r = 0; r < 4; ++r) {
          float s = ST(wave, quad * 4 + r, l16) + acc[r];
          ST(wave, quad * 4 + r, l16) = s;
        }
      }
      __syncthreads();
      {
        const int b = tid >> 4;
        const int jl = tid & 15;
        const int w = b >> 4, bl = b & 15;
        float v = tanhf(ST(w, bl, jl) + ST(w + 4, bl, jl));
        p.outs[(size_t)t * B_ * H_ + b * H_ + pj0 + jl] = v;
        unsigned u = f2bf(v);
        unsigned up = __shfl_down(u, 1);
        if (!(jl & 1))
          st32_dev((unsigned*)feedw + b * (H_ / 2) + blk * 8 + (jl >> 1),
                   u | (up << 16));
      }
    }
    grid_bar(p.flags, ++gen);
  }
}

// ---------------------------------------------------------------------------
extern "C" void kernel_launch(void* const* d_in, const int* in_sizes, int n_in,
                              void* d_out, int out_size, void* d_ws, size_t ws_size,
                              hipStream_t stream) {
  const float* inpf  = (const float*)d_in[0];
  const float* ctxf  = (const float*)d_in[1];
  const float* h0in  = (const float*)d_in[2];
  const float* c0in  = (const float*)d_in[3];
  const float* Wih0f = (const float*)d_in[4];
  const float* bih0  = (const float*)d_in[5];
  const float* Whh0f = (const float*)d_in[6];
  const float* bhh0  = (const float*)d_in[7];
  const float* Wih1f = (const float*)d_in[8];
  const float* bih1  = (const float*)d_in[9];
  const float* Whh1f = (const float*)d_in[10];
  const float* bhh1  = (const float*)d_in[11];
  const float* Waf   = (const float*)d_in[12];
  const float* Woutf = (const float*)d_in[13];

  float* out = (float*)d_out;
  float* outs  = out;                              // (T,B,H)
  float* hF    = out + (size_t)T_ * B_ * H_;       // (2,B,H)
  float* cF    = hF + 2 * BH;                      // (2,B,H)
  float* attns = cF + 2 * BH;                      // (T,B,S)

  char* p = (char*)d_ws;
  auto take = [&](size_t bytes) -> char* {
    char* q = p;
    p += (bytes + 255) & ~(size_t)255;
    return q;
  };
  ushort* h0b  = (ushort*)take((size_t)(T_ + 1) * BH * 2);
  ushort* h1b  = (ushort*)take((size_t)(T_ + 1) * BH * 2);
  ushort* fdb  = (ushort*)take((size_t)(T_ + 1) * BH * 2);
  ushort* cvb  = (ushort*)take((size_t)T_ * BH * 2);
  float* psb   = (float*)take((size_t)T_ * B_ * S_ * 4 * 4);
  unsigned* flags = (unsigned*)take(256 * 16 * sizeof(unsigned));
  ushort* WaT  = (ushort*)take((size_t)H_ * H_ * 2);
  ushort* ctxp = (ushort*)take((size_t)S_ * B_ * H_ * 2);

  struct { const float* src; int n; } cv[7] = {
    {Wih0f, 4 * H_ * (E_ + H_)}, {Whh0f, 4 * H_ * H_},
    {Wih1f, 4 * H_ * H_},        {Whh1f, 4 * H_ * H_},
    {Woutf, 2 * H_ * H_},
    {inpf,  T_ * B_ * E_},       {ctxf,  S_ * B_ * H_},
  };
  ushort* cb[7];
  for (int i = 0; i < 7; ++i) {
    cb[i] = (ushort*)take((size_t)cv[i].n * 2);
    int n4 = cv[i].n / 4;
    k_cvt<<<(n4 + 255) / 256, 256, 0, stream>>>(cv[i].src, cb[i], n4);
  }
  const ushort *Wih0 = cb[0], *Whh0 = cb[1], *Wih1 = cb[2], *Whh1 = cb[3],
               *Wout = cb[4], *inp = cb[5], *ctx = cb[6];

  k_cvtT<<<(H_ / 32) * (H_ / 32), 256, 0, stream>>>(Waf, WaT);
  k_ctxp<<<dim3((S_ * B_) / 64, H_ / 64), 256, 0, stream>>>(ctx, WaT, ctxp);
  k_init<<<BH / 256, 256, 0, stream>>>(h0in, h0b, h1b, fdb, flags);

  static int smem_set = 0;
  if (!smem_set) {
    hipFuncSetAttribute((const void*)k_fused,
                        hipFuncAttributeMaxDynamicSharedMemorySize, SMEM_BYTES);
    smem_set = 1;
  }

  FusedP fp;
  fp.inp = inp; fp.Wih0 = Wih0; fp.Whh0 = Whh0; fp.Wih1 = Wih1; fp.Whh1 = Whh1;
  fp.Wout = Wout; fp.ctx = ctx; fp.ctxp = ctxp;
  fp.bih0 = bih0; fp.bhh0 = bhh0; fp.bih1 = bih1; fp.bhh1 = bhh1;
  fp.c0in = c0in;
  fp.h0b = h0b; fp.h1b = h1b; fp.fdb = fdb; fp.cvb = cvb; fp.psb = psb;
  fp.outs = outs; fp.hF = hF; fp.cF = cF; fp.attns = attns;
  fp.flags = flags;
  void* kargs[] = {(void*)&fp};
  hipLaunchCooperativeKernel(k_fused, dim3(256), dim3(1024), kargs,
                             (unsigned)SMEM_BYTES, stream);
}

// Round 12
// 2864.630 us; speedup vs baseline: 1.3529x; 1.1551x over previous
//
#include <hip/hip_runtime.h>

#define T_ 64
#define B_ 64
#define S_ 128
#define E_ 512
#define H_ 1024
#define BH (B_ * H_)

// LDS weight slice geometry (bf16 elements), +8 pad => row stride = 4 banks
#define W0ROW (E_ + 2 * H_ + 8)   // 2568
#define W1ROW (2 * H_ + 8)        // 2056
#define SMEM_BYTES ((16 * W0ROW + 16 * W1ROW) * 2)  // 147968 B

typedef __attribute__((ext_vector_type(8))) short short8;
typedef __attribute__((ext_vector_type(4))) short short4v;
typedef __attribute__((ext_vector_type(4))) float f32x4;

static __device__ __forceinline__ float bf2f(ushort u) {
  union { float f; unsigned u; } x; x.u = ((unsigned)u) << 16; return x.f;
}
static __device__ __forceinline__ ushort f2bf(float f) {
  union { float f; unsigned u; } x; x.f = f;
  unsigned r = 0x7FFFu + ((x.u >> 16) & 1u);
  return (ushort)((x.u + r) >> 16);
}
static __device__ __forceinline__ float sigm(float x) {
  return 1.f / (1.f + expf(-x));
}

// device-scope (sc1) relaxed atomics: write-through to the coherence point.
static __device__ __forceinline__ void st32_dev(unsigned* p, unsigned v) {
  __hip_atomic_store(p, v, __ATOMIC_RELAXED, __HIP_MEMORY_SCOPE_AGENT);
}
static __device__ __forceinline__ unsigned ld32_dev(const unsigned* p) {
  return __hip_atomic_load(p, __ATOMIC_RELAXED, __HIP_MEMORY_SCOPE_AGENT);
}
static __device__ __forceinline__ void stf_dev(float* p, float v) {
  union { float f; unsigned u; } x; x.f = v;
  st32_dev((unsigned*)p, x.u);
}

// ---------------------------------------------------------------------------
__global__ __launch_bounds__(256) void k_cvt(const float* __restrict__ src,
                                             ushort* __restrict__ dst, int n4) {
  int i = blockIdx.x * 256 + threadIdx.x;
  if (i >= n4) return;
  f32x4 v = ((const f32x4*)src)[i];
  short4v o;
  o[0] = (short)f2bf(v[0]); o[1] = (short)f2bf(v[1]);
  o[2] = (short)f2bf(v[2]); o[3] = (short)f2bf(v[3]);
  ((short4v*)dst)[i] = o;
}

// ---------------------------------------------------------------------------
// f32 (H,H) [k][d]  ->  bf16 (H,H) [d][k]  (transpose + convert, LDS tiled)
__global__ __launch_bounds__(256) void k_cvtT(const float* __restrict__ src,
                                              ushort* __restrict__ dst) {
  __shared__ ushort tile[32][33];
  const int bx = blockIdx.x & 31;   // d-tile
  const int by = blockIdx.x >> 5;   // k-tile
  const int lx = threadIdx.x & 31, ly = threadIdx.x >> 5;  // 32 x 8
#pragma unroll
  for (int i = 0; i < 32; i += 8)
    tile[ly + i][lx] = f2bf(src[(size_t)(by * 32 + ly + i) * H_ + bx * 32 + lx]);
  __syncthreads();
#pragma unroll
  for (int i = 0; i < 32; i += 8)
    dst[(size_t)(bx * 32 + ly + i) * H_ + by * 32 + lx] = tile[lx][ly + i];
}

// ---------------------------------------------------------------------------
// ctxp[m, d] = sum_k ctx[m, k] * WaT[d, k],  m = s*B+b.  bf16 output.
__global__ __launch_bounds__(256) void k_ctxp(const ushort* __restrict__ ctx,
                                              const ushort* __restrict__ WaT,
                                              ushort* __restrict__ ctxp) {
  const int tid = threadIdx.x;
  const int wave = tid >> 6, lane = tid & 63;
  const int quad = lane >> 4, l16 = lane & 15;
  const int m0 = blockIdx.x * 64 + wave * 16;
  const int n0 = blockIdx.y * 64;
  const ushort* ar = ctx + (size_t)(m0 + l16) * H_;
  const int koff = quad * 8;
  f32x4 acc[4] = {};
  for (int k0 = 0; k0 < H_; k0 += 32) {
    int kk = k0 + koff;
    short8 a = *(const short8*)(ar + kk);
#pragma unroll
    for (int nt = 0; nt < 4; ++nt) {
      short8 b = *(const short8*)(WaT + (size_t)(n0 + nt * 16 + l16) * H_ + kk);
      acc[nt] = __builtin_amdgcn_mfma_f32_16x16x32_bf16(a, b, acc[nt], 0, 0, 0);
    }
  }
#pragma unroll
  for (int nt = 0; nt < 4; ++nt)
#pragma unroll
    for (int r = 0; r < 4; ++r)
      ctxp[(size_t)(m0 + quad * 4 + r) * H_ + n0 + nt * 16 + l16] =
          f2bf(acc[nt][r]);
}

// ---------------------------------------------------------------------------
// ctxo[m, j] = sum_d ctx[m, d] * Wout[j, d]  (first-H cols of Wout).  bf16.
// (r8-verified)
__global__ __launch_bounds__(256) void k_ctxo(const ushort* __restrict__ ctx,
                                              const ushort* __restrict__ Wout,
                                              ushort* __restrict__ ctxo) {
  const int tid = threadIdx.x;
  const int wave = tid >> 6, lane = tid & 63;
  const int quad = lane >> 4, l16 = lane & 15;
  const int m0 = blockIdx.x * 64 + wave * 16;
  const int n0 = blockIdx.y * 64;
  const ushort* ar = ctx + (size_t)(m0 + l16) * H_;
  const int koff = quad * 8;
  f32x4 acc[4] = {};
  for (int k0 = 0; k0 < H_; k0 += 32) {
    int kk = k0 + koff;
    short8 a = *(const short8*)(ar + kk);
#pragma unroll
    for (int nt = 0; nt < 4; ++nt) {
      short8 b = *(const short8*)(Wout +
                                  (size_t)(n0 + nt * 16 + l16) * (2 * H_) + kk);
      acc[nt] = __builtin_amdgcn_mfma_f32_16x16x32_bf16(a, b, acc[nt], 0, 0, 0);
    }
  }
#pragma unroll
  for (int nt = 0; nt < 4; ++nt)
#pragma unroll
    for (int r = 0; r < 4; ++r)
      ctxo[(size_t)(m0 + quad * 4 + r) * H_ + n0 + nt * 16 + l16] =
          f2bf(acc[nt][r]);
}

// ---------------------------------------------------------------------------
__global__ __launch_bounds__(256) void k_init(const float* __restrict__ h0in,
                                              ushort* __restrict__ h0b,
                                              ushort* __restrict__ h1b,
                                              ushort* __restrict__ fdb,
                                              unsigned* __restrict__ flags) {
  int i = blockIdx.x * 256 + threadIdx.x;
  h0b[i] = f2bf(h0in[i]);
  h1b[i] = f2bf(h0in[BH + i]);
  fdb[i] = 0;
  if (blockIdx.x == 0) flags[threadIdx.x * 16] = 0;
}

// ---------------------------------------------------------------------------
// Grid barrier (round-3/7/11 proven): block 0 collects per-block arrival
// flags, broadcasts via flags[0]. sc1 stores reach the coherence point;
// __syncthreads drains vmcnt. No cache-invalidating fences.
static __device__ __forceinline__ void grid_bar(unsigned* flags, unsigned gen) {
  __syncthreads();
  if (blockIdx.x == 0) {
    const int tid = threadIdx.x;
    if (tid > 0 && tid < 256) {
      while (ld32_dev(&flags[tid * 16]) < gen) __builtin_amdgcn_s_sleep(4);
    }
    __syncthreads();
    if (tid == 0) st32_dev(&flags[0], gen);
    __syncthreads();
  } else {
    if (threadIdx.x == 0) {
      st32_dev(&flags[blockIdx.x * 16], gen);
      while (ld32_dev(&flags[0]) < gen) __builtin_amdgcn_s_sleep(4);
    }
    __syncthreads();
  }
  asm volatile("" ::: "memory");
}

// ---------------------------------------------------------------------------
struct FusedP {
  const ushort* inp;
  const ushort* Wih0; const ushort* Whh0;
  const ushort* Wih1; const ushort* Whh1;
  const ushort* Wout;
  const ushort* ctxp;    // bf16 (S,B,H) = ctx @ Wa
  const ushort* ctxo;    // bf16 (S,B,H) = ctx @ Wout_c^T
  const float* bih0; const float* bhh0;
  const float* bih1; const float* bhh1;
  const float* c0in;
  ushort* h0b;   // (T_+1) rotated (B,H) bf16 buffers -- write-once
  ushort* h1b;   // (T_+1)
  ushort* fdb;   // (T_+1)
  float* psb;    // (T_) rotated (B,S,4) f32 partial scores -- write-once
  float* gemmb;  // (T_) rotated (B,H) f32 h1@Wout_h^T -- write-once
  float* outs; float* hF; float* cF; float* attns;
  unsigned* flags;
};

// st/red union over ub[]:  st[w][r][c] (8x16x17)  /  red[w][i] (8x256)
#define ST(w, r, c) ub[(w) * 272 + (r) * 17 + (c)]
#define RED(w, i)   ub[(w) * 256 + (i)]

// Persistent kernel: 256 blocks x 1024 threads (4 waves/SIMD), now 4
// barriers/step (was 5). Schedule: P1 lstm0 | P2 lstm1 | P3 {scores from
// pinned ctxp (all blocks) + gemmh = h1@Wout_h^T (blocks 0..63)} | P4
// {softmax + attn-sum from pinned ctxo + gemmh combine + outs/feed}.
// The old cvec/cv buffer and its barrier are gone (ctxo factorization,
// r8-verified); ctx pins replaced by ctxo pins (same register count).
__global__ __launch_bounds__(1024, 1) void k_fused(FusedP p) {
  extern __shared__ ushort wlds[];          // [16*W0ROW] + [16*W1ROW]
  ushort* w0 = wlds;
  ushort* w1 = wlds + 16 * W0ROW;
  __shared__ float ub[2176];                // st / red union (8704 B)
  __shared__ float al[S_];
  const int blk = blockIdx.x;
  const int tid = threadIdx.x;
  const int wave = tid >> 6, lane = tid & 63;
  const int wg = wave & 3;                  // batch strip
  const int kh = wave >> 2;                 // K-quarter
  const int quad = lane >> 4, l16 = lane & 15;
  const int j0 = blk * 4;

  // ---- stage this block's weight slice into LDS (once) ----
  for (int idx = tid; idx < 16 * 192; idx += 1024) {   // Wih0
    int r = idx / 192, c = (idx % 192) * 8;
    int n = (r >> 2) * H_ + j0 + (r & 3);
    *(short8*)(w0 + r * W0ROW + c) =
        *(const short8*)(p.Wih0 + (size_t)n * (E_ + H_) + c);
  }
  for (int idx = tid; idx < 16 * 128; idx += 1024) {   // Whh0
    int r = idx / 128, c = (idx % 128) * 8;
    int n = (r >> 2) * H_ + j0 + (r & 3);
    *(short8*)(w0 + r * W0ROW + (E_ + H_) + c) =
        *(const short8*)(p.Whh0 + (size_t)n * H_ + c);
  }
  for (int idx = tid; idx < 16 * 128; idx += 1024) {   // Wih1
    int r = idx / 128, c = (idx % 128) * 8;
    int n = (r >> 2) * H_ + j0 + (r & 3);
    *(short8*)(w1 + r * W1ROW + c) =
        *(const short8*)(p.Wih1 + (size_t)n * H_ + c);
  }
  for (int idx = tid; idx < 16 * 128; idx += 1024) {   // Whh1
    int r = idx / 128, c = (idx % 128) * 8;
    int n = (r >> 2) * H_ + j0 + (r & 3);
    *(short8*)(w1 + r * W1ROW + H_ + c) =
        *(const short8*)(p.Whh1 + (size_t)n * H_ + c);
  }
  __syncthreads();

  // cell ownership (tid<256): cell = tid -> b = tid>>2, jl = tid&3
  const int own_b = tid >> 2;
  const int own_jl = tid & 3;
  const int own_j = j0 + own_jl;
  const int own_idx = own_b * H_ + own_j;
  float c0reg = 0.f, c1reg = 0.f;
  float b0i = 0.f, b0f = 0.f, b0g = 0.f, b0o = 0.f;
  float b1i = 0.f, b1f = 0.f, b1g = 0.f, b1o = 0.f;
  if (tid < 256) {
    c0reg = p.c0in[own_idx];
    c1reg = p.c0in[BH + own_idx];
    b0i = p.bih0[own_j]          + p.bhh0[own_j];
    b0f = p.bih0[H_ + own_j]     + p.bhh0[H_ + own_j];
    b0g = p.bih0[2 * H_ + own_j] + p.bhh0[2 * H_ + own_j];
    b0o = p.bih0[3 * H_ + own_j] + p.bhh0[3 * H_ + own_j];
    b1i = p.bih1[own_j]          + p.bhh1[own_j];
    b1f = p.bih1[H_ + own_j]     + p.bhh1[H_ + own_j];
    b1g = p.bih1[2 * H_ + own_j] + p.bhh1[2 * H_ + own_j];
    b1o = p.bih1[3 * H_ + own_j] + p.bhh1[3 * H_ + own_j];
  }

  const ushort* w0r = w0 + l16 * W0ROW;   // B-fragment row for MFMA
  const ushort* w1r = w1 + l16 * W1ROW;
  const int koff = quad * 8;

  // attention decomposition: this block owns (b3, d-quarter dq)
  const int b3 = blk >> 2, dq = blk & 3;
  const int d0 = dq * 256;

  // ---- register-pinned attention slices (time-invariant) ----
  short4v cp[8], co[8];
#pragma unroll
  for (int i = 0; i < 8; ++i) {
    const int s = wave * 8 + i;
    cp[i] = *(const short4v*)(p.ctxp + ((size_t)s * B_ + b3) * H_ +
                              d0 + lane * 4);
    co[i] = *(const short4v*)(p.ctxo + ((size_t)s * B_ + b3) * H_ +
                              d0 + lane * 4);
  }

  unsigned gen = 0;

  for (int t = 0; t < T_; ++t) {
    const ushort* h0prev = p.h0b + (size_t)t * BH;
    ushort* h0new       = p.h0b + (size_t)(t + 1) * BH;
    const ushort* h1prev = p.h1b + (size_t)t * BH;
    ushort* h1new       = p.h1b + (size_t)(t + 1) * BH;
    const ushort* feedr  = p.fdb + (size_t)t * BH;
    ushort* feedw       = p.fdb + (size_t)(t + 1) * BH;
    float* pst          = p.psb + (size_t)t * B_ * S_ * 4;
    float* gemm_t       = p.gemmb + (size_t)t * BH;
    const int last = (t == T_ - 1);

    // ---- phase 1: LSTM layer 0, 4-way K-split ----
    {
      const int arow = 16 * wg + l16;
      const ushort* er = p.inp + ((size_t)t * B_ + arow) * E_;
      const ushort* fr = feedr + (size_t)arow * H_;
      const ushort* hr = h0prev + (size_t)arow * H_;
      const int kbase = kh * 640;           // (E+2H)/4
      f32x4 acc = {};
#pragma unroll
      for (int k0 = 0; k0 < 640; k0 += 32) {
        int kk = kbase + k0 + koff;
        short8 a;
        if (kk < E_)            a = *(const short8*)(er + kk);
        else if (kk < E_ + H_)  a = *(const short8*)(fr + (kk - E_));
        else                    a = *(const short8*)(hr + (kk - E_ - H_));
        short8 b = *(const short8*)(w0r + kk);
        acc = __builtin_amdgcn_mfma_f32_16x16x32_bf16(a, b, acc, 0, 0, 0);
      }
      if (kh >= 2) {
#pragma unroll
        for (int r = 0; r < 4; ++r) ST(wave - 8, quad * 4 + r, l16) = acc[r];
      }
      __syncthreads();
      if (kh < 2) {
#pragma unroll
        for (int r = 0; r < 4; ++r) {
          float s = ST(wave, quad * 4 + r, l16) + acc[r];
          ST(wave, quad * 4 + r, l16) = s;
        }
      }
      __syncthreads();
      if (tid < 256) {
        const int w = own_b >> 4, bl = own_b & 15;
        float gi = ST(w, bl, 0 + own_jl)  + ST(w + 4, bl, 0 + own_jl)  + b0i;
        float gf = ST(w, bl, 4 + own_jl)  + ST(w + 4, bl, 4 + own_jl)  + b0f;
        float gg = ST(w, bl, 8 + own_jl)  + ST(w + 4, bl, 8 + own_jl)  + b0g;
        float go = ST(w, bl, 12 + own_jl) + ST(w + 4, bl, 12 + own_jl) + b0o;
        float cn = sigm(gf) * c0reg + sigm(gi) * tanhf(gg);
        float hn = sigm(go) * tanhf(cn);
        c0reg = cn;
        if (last) { p.hF[own_idx] = hn; p.cF[own_idx] = cn; }
        unsigned u = f2bf(hn);
        unsigned up = __shfl_down(u, 1);
        if (!(own_jl & 1))
          st32_dev((unsigned*)h0new + own_b * (H_ / 2) + blk * 2 + (own_jl >> 1),
                   u | (up << 16));
      }
    }
    grid_bar(p.flags, ++gen);

    // ---- phase 2: LSTM layer 1, 4-way K-split ----
    {
      const int arow = 16 * wg + l16;
      const ushort* xr = h0new + (size_t)arow * H_;
      const ushort* hr = h1prev + (size_t)arow * H_;
      const int kbase = kh * 512;           // 2H/4
      f32x4 acc = {};
#pragma unroll
      for (int k0 = 0; k0 < 512; k0 += 32) {
        int kk = kbase + k0 + koff;
        short8 a = (kk < H_) ? *(const short8*)(xr + kk)
                             : *(const short8*)(hr + (kk - H_));
        short8 b = *(const short8*)(w1r + kk);
        acc = __builtin_amdgcn_mfma_f32_16x16x32_bf16(a, b, acc, 0, 0, 0);
      }
      if (kh >= 2) {
#pragma unroll
        for (int r = 0; r < 4; ++r) ST(wave - 8, quad * 4 + r, l16) = acc[r];
      }
      __syncthreads();
      if (kh < 2) {
#pragma unroll
        for (int r = 0; r < 4; ++r) {
          float s = ST(wave, quad * 4 + r, l16) + acc[r];
          ST(wave, quad * 4 + r, l16) = s;
        }
      }
      __syncthreads();
      if (tid < 256) {
        const int w = own_b >> 4, bl = own_b & 15;
        float gi = ST(w, bl, 0 + own_jl)  + ST(w + 4, bl, 0 + own_jl)  + b1i;
        float gf = ST(w, bl, 4 + own_jl)  + ST(w + 4, bl, 4 + own_jl)  + b1f;
        float gg = ST(w, bl, 8 + own_jl)  + ST(w + 4, bl, 8 + own_jl)  + b1g;
        float go = ST(w, bl, 12 + own_jl) + ST(w + 4, bl, 12 + own_jl) + b1o;
        float cn = sigm(gf) * c1reg + sigm(gi) * tanhf(gg);
        float hn = sigm(go) * tanhf(cn);
        c1reg = cn;
        if (last) { p.hF[BH + own_idx] = hn; p.cF[BH + own_idx] = cn; }
        unsigned u = f2bf(hn);
        unsigned up = __shfl_down(u, 1);
        if (!(own_jl & 1))
          st32_dev((unsigned*)h1new + own_b * (H_ / 2) + blk * 2 + (own_jl >> 1),
                   u | (up << 16));
      }
    }
    grid_bar(p.flags, ++gen);

    // ---- phase 3: scores from PINNED ctxp (all) + gemmh (blocks 0..63) ----
    {
      short4v qv = *(const short4v*)(h1new + (size_t)b3 * H_ + d0 + lane * 4);
      float q0 = bf2f((ushort)qv[0]), q1 = bf2f((ushort)qv[1]);
      float q2 = bf2f((ushort)qv[2]), q3 = bf2f((ushort)qv[3]);
#pragma unroll
      for (int i = 0; i < 8; ++i) {
        const int s = wave * 8 + i;
        float pr = bf2f((ushort)cp[i][0]) * q0 + bf2f((ushort)cp[i][1]) * q1 +
                   bf2f((ushort)cp[i][2]) * q2 + bf2f((ushort)cp[i][3]) * q3;
#pragma unroll
        for (int off = 32; off; off >>= 1) pr += __shfl_down(pr, off);
        if (lane == 0) stf_dev(pst + (b3 * S_ + s) * 4 + dq, pr);
      }
      // gemmh: blocks 0..63 own 16 j-cols; K=1024 (h1 half of Wout)
      if (blk < 64) {
        const int pj0 = blk * 16;
        const int arow = 16 * wg + l16;
        const ushort* hr2 = h1new + (size_t)arow * H_;
        const ushort* wr = p.Wout + (size_t)(pj0 + l16) * (2 * H_) + H_;
        const int kbase = kh * 256;
        f32x4 acc = {};
#pragma unroll
        for (int k0 = 0; k0 < 256; k0 += 32) {
          int kk = kbase + k0 + koff;
          acc = __builtin_amdgcn_mfma_f32_16x16x32_bf16(
              *(const short8*)(hr2 + kk), *(const short8*)(wr + kk), acc,
              0, 0, 0);
        }
        if (kh >= 2) {
#pragma unroll
          for (int r = 0; r < 4; ++r) ST(wave - 8, quad * 4 + r, l16) = acc[r];
        }
        __syncthreads();
        if (kh < 2) {
#pragma unroll
          for (int r = 0; r < 4; ++r) {
            float s = ST(wave, quad * 4 + r, l16) + acc[r];
            ST(wave, quad * 4 + r, l16) = s;
          }
        }
        __syncthreads();
        {
          const int b = tid >> 4;
          const int jl = tid & 15;
          const int w = b >> 4, bl = b & 15;
          stf_dev(gemm_t + b * H_ + pj0 + jl,
                  ST(w, bl, jl) + ST(w + 4, bl, jl));
        }
      }
    }
    grid_bar(p.flags, ++gen);

    // ---- phase 4: softmax + attn-sum from PINNED ctxo + combine ----
    {
      if (tid < S_) {
        f32x4 ps = *(const f32x4*)(pst + (b3 * S_ + tid) * 4);
        al[tid] = ps[0] + ps[1] + ps[2] + ps[3];
      }
      __syncthreads();
      if (wave == 0) {
        float m = fmaxf(al[lane], al[lane + 64]);
#pragma unroll
        for (int off = 32; off; off >>= 1) m = fmaxf(m, __shfl_down(m, off));
        m = __shfl(m, 0);
        float e0 = expf(al[lane] - m), e1 = expf(al[lane + 64] - m);
        float s2 = e0 + e1;
#pragma unroll
        for (int off = 32; off; off >>= 1) s2 += __shfl_down(s2, off);
        s2 = __shfl(s2, 0);
        float inv = 1.f / s2;
        al[lane] = e0 * inv;
        al[lane + 64] = e1 * inv;
      }
      __syncthreads();
      if (dq == 0 && tid < S_)
        p.attns[((size_t)t * B_ + b3) * S_ + tid] = al[tid];
      // attn part of outs over d-quarter: wave w covers s in [8w, 8w+8)
      float a0 = 0.f, a1 = 0.f, a2 = 0.f, a3 = 0.f;
#pragma unroll
      for (int i = 0; i < 8; ++i) {
        const int s = wave * 8 + i;
        float w = al[s];
        a0 += w * bf2f((ushort)co[i][0]);
        a1 += w * bf2f((ushort)co[i][1]);
        a2 += w * bf2f((ushort)co[i][2]);
        a3 += w * bf2f((ushort)co[i][3]);
      }
      __syncthreads();   // al reads done; ub reuse safe (last used in P3)
      if (wave >= 8) {
        RED(wave - 8, lane * 4 + 0) = a0;
        RED(wave - 8, lane * 4 + 1) = a1;
        RED(wave - 8, lane * 4 + 2) = a2;
        RED(wave - 8, lane * 4 + 3) = a3;
      }
      __syncthreads();
      if (wave < 8) {
        RED(wave, lane * 4 + 0) += a0;
        RED(wave, lane * 4 + 1) += a1;
        RED(wave, lane * 4 + 2) += a2;
        RED(wave, lane * 4 + 3) += a3;
      }
      __syncthreads();
      if (tid < 256) {
        const int jj = tid;
        float val = 0.f;
#pragma unroll
        for (int w = 0; w < 8; ++w) val += RED(w, jj);
        val += gemm_t[b3 * H_ + d0 + jj];
        float v = tanhf(val);
        p.outs[(size_t)t * B_ * H_ + b3 * H_ + d0 + jj] = v;
        unsigned u = f2bf(v);
        unsigned up = __shfl_down(u, 1);
        if (!(jj & 1))
          st32_dev((unsigned*)feedw + (b3 * H_ + d0 + jj) / 2, u | (up << 16));
      }
    }
    grid_bar(p.flags, ++gen);
  }
}

// ---------------------------------------------------------------------------
extern "C" void kernel_launch(void* const* d_in, const int* in_sizes, int n_in,
                              void* d_out, int out_size, void* d_ws, size_t ws_size,
                              hipStream_t stream) {
  const float* inpf  = (const float*)d_in[0];
  const float* ctxf  = (const float*)d_in[1];
  const float* h0in  = (const float*)d_in[2];
  const float* c0in  = (const float*)d_in[3];
  const float* Wih0f = (const float*)d_in[4];
  const float* bih0  = (const float*)d_in[5];
  const float* Whh0f = (const float*)d_in[6];
  const float* bhh0  = (const float*)d_in[7];
  const float* Wih1f = (const float*)d_in[8];
  const float* bih1  = (const float*)d_in[9];
  const float* Whh1f = (const float*)d_in[10];
  const float* bhh1  = (const float*)d_in[11];
  const float* Waf   = (const float*)d_in[12];
  const float* Woutf = (const float*)d_in[13];

  float* out = (float*)d_out;
  float* outs  = out;                              // (T,B,H)
  float* hF    = out + (size_t)T_ * B_ * H_;       // (2,B,H)
  float* cF    = hF + 2 * BH;                      // (2,B,H)
  float* attns = cF + 2 * BH;                      // (T,B,S)

  char* p = (char*)d_ws;
  auto take = [&](size_t bytes) -> char* {
    char* q = p;
    p += (bytes + 255) & ~(size_t)255;
    return q;
  };
  ushort* h0b  = (ushort*)take((size_t)(T_ + 1) * BH * 2);
  ushort* h1b  = (ushort*)take((size_t)(T_ + 1) * BH * 2);
  ushort* fdb  = (ushort*)take((size_t)(T_ + 1) * BH * 2);
  float* psb   = (float*)take((size_t)T_ * B_ * S_ * 4 * 4);
  float* gemmb = (float*)take((size_t)T_ * BH * 4);
  unsigned* flags = (unsigned*)take(256 * 16 * sizeof(unsigned));
  ushort* WaT  = (ushort*)take((size_t)H_ * H_ * 2);
  ushort* ctxp = (ushort*)take((size_t)S_ * B_ * H_ * 2);
  ushort* ctxo = (ushort*)take((size_t)S_ * B_ * H_ * 2);

  struct { const float* src; int n; } cv[7] = {
    {Wih0f, 4 * H_ * (E_ + H_)}, {Whh0f, 4 * H_ * H_},
    {Wih1f, 4 * H_ * H_},        {Whh1f, 4 * H_ * H_},
    {Woutf, 2 * H_ * H_},
    {inpf,  T_ * B_ * E_},       {ctxf,  S_ * B_ * H_},
  };
  ushort* cb[7];
  for (int i = 0; i < 7; ++i) {
    cb[i] = (ushort*)take((size_t)cv[i].n * 2);
    int n4 = cv[i].n / 4;
    k_cvt<<<(n4 + 255) / 256, 256, 0, stream>>>(cv[i].src, cb[i], n4);
  }
  const ushort *Wih0 = cb[0], *Whh0 = cb[1], *Wih1 = cb[2], *Whh1 = cb[3],
               *Wout = cb[4], *inp = cb[5], *ctx = cb[6];

  k_cvtT<<<(H_ / 32) * (H_ / 32), 256, 0, stream>>>(Waf, WaT);
  k_ctxp<<<dim3((S_ * B_) / 64, H_ / 64), 256, 0, stream>>>(ctx, WaT, ctxp);
  k_ctxo<<<dim3((S_ * B_) / 64, H_ / 64), 256, 0, stream>>>(ctx, Wout, ctxo);
  k_init<<<BH / 256, 256, 0, stream>>>(h0in, h0b, h1b, fdb, flags);

  static int smem_set = 0;
  if (!smem_set) {
    hipFuncSetAttribute((const void*)k_fused,
                        hipFuncAttributeMaxDynamicSharedMemorySize, SMEM_BYTES);
    smem_set = 1;
  }

  FusedP fp;
  fp.inp = inp; fp.Wih0 = Wih0; fp.Whh0 = Whh0; fp.Wih1 = Wih1; fp.Whh1 = Whh1;
  fp.Wout = Wout; fp.ctxp = ctxp; fp.ctxo = ctxo;
  fp.bih0 = bih0; fp.bhh0 = bhh0; fp.bih1 = bih1; fp.bhh1 = bhh1;
  fp.c0in = c0in;
  fp.h0b = h0b; fp.h1b = h1b; fp.fdb = fdb; fp.psb = psb; fp.gemmb = gemmb;
  fp.outs = outs; fp.hF = hF; fp.cF = cF; fp.attns = attns;
  fp.flags = flags;
  void* kargs[] = {(void*)&fp};
  hipLaunchCooperativeKernel(k_fused, dim3(256), dim3(1024), kargs,
                             (unsigned)SMEM_BYTES, stream);
}